// Round 9
// baseline (610.575 us; speedup 1.0000x reference)
//
#include <hip/hip_runtime.h>
#include <math.h>

#define NN 200000
#define NE 3200000
#define NF 128
#define NG 1000
#define KSEL 30
#define CCAT 97
#define NPAD 200704      // 196 * 1024, padded node count for the scan
#define SCAN_BLKS 196
#define EPADCAP (NE + 8 * NN)     // padded-CSR esrc capacity

#define BWID 512                  // nodes per bucket (dst >> 9)
#define NB 391                    // ceil(NN / BWID)
#define BCAP 10240                // per-bucket edge capacity (mean 8184, sigma ~90)
#define P1_CHUNK 8192             // edges per block in partition pass
#define P1_BLKS 391               // ceil(NE / P1_CHUNK)

// ---------------- pass 1: partition edges into dst-buckets ----------------
__global__ void k_p1_partition(const int* __restrict__ ei, int* __restrict__ bcursor,
                               int* __restrict__ ebuf) {
    __shared__ int lhist[NB];
    __shared__ int lbase[NB];
    int tid = threadIdx.x;
    int base = blockIdx.x * P1_CHUNK;
    for (int b = tid; b < NB; b += 256) lhist[b] = 0;
    __syncthreads();
    for (int it = 0; it < P1_CHUNK / 256; it++) {
        int e = base + it * 256 + tid;
        if (e < NE) {
            int s = ei[e], d = ei[NE + e];
            if (s != d) atomicAdd(&lhist[d >> 9], 1);
        }
    }
    __syncthreads();
    for (int b = tid; b < NB; b += 256) {
        int cnt = lhist[b];
        lbase[b] = cnt ? atomicAdd(&bcursor[b], cnt) : 0;
        lhist[b] = 0;
    }
    __syncthreads();
    for (int it = 0; it < P1_CHUNK / 256; it++) {
        int e = base + it * 256 + tid;
        if (e < NE) {
            int s = ei[e], d = ei[NE + e];
            if (s != d) {
                int b = d >> 9;
                int r = atomicAdd(&lhist[b], 1);
                int pos = lbase[b] + r;
                if (pos >= BCAP) pos = BCAP - 1;  // defensive (cannot happen)
                ebuf[b * BCAP + pos] = s | ((d & 511) << 18);
            }
        }
    }
}

// ---------------- pass 2: per-bucket node counts + inv_sqrt ----------------
__global__ void k_p2_count(const int* __restrict__ bcursor, const int* __restrict__ ebuf,
                           int* __restrict__ rowcnt, float* __restrict__ inv_sqrt) {
    __shared__ int lcnt[BWID];
    int b = blockIdx.x;
    int tid = threadIdx.x;
    for (int i = tid; i < BWID; i += 256) lcnt[i] = 0;
    __syncthreads();
    int size = bcursor[b];
    if (size > BCAP) size = BCAP;
    const int* eb = ebuf + b * BCAP;
    for (int k = tid; k < size; k += 256) atomicAdd(&lcnt[eb[k] >> 18], 1);
    __syncthreads();
    int node0 = b * BWID;
    for (int i = tid; i < BWID; i += 256) {
        int node = node0 + i;
        if (node < NN) {
            int c = lcnt[i];
            rowcnt[node] = (c + 7) & ~7;
            inv_sqrt[node] = rsqrtf((float)(c + 1));
        }
    }
}

// ---------------- scan (rowcnt -> rowstart, exclusive) ----------------
__global__ void k_scanA(const int* __restrict__ in, int* __restrict__ out,
                        int* __restrict__ bsums) {
    __shared__ int s[1024];
    int tid = threadIdx.x;
    int gid = blockIdx.x * 1024 + tid;
    int v = in[gid];
    s[tid] = v;
    __syncthreads();
    for (int off = 1; off < 1024; off <<= 1) {
        int a = (tid >= off) ? s[tid - off] : 0;
        int cur = s[tid];
        __syncthreads();
        s[tid] = cur + a;
        __syncthreads();
    }
    out[gid] = s[tid] - v;
    if (tid == 1023) bsums[blockIdx.x] = s[tid];
}

__global__ void k_scanB(int* __restrict__ bsums) {
    __shared__ int s[256];
    int tid = threadIdx.x;
    int v = (tid < SCAN_BLKS) ? bsums[tid] : 0;
    s[tid] = v;
    __syncthreads();
    for (int off = 1; off < 256; off <<= 1) {
        int a = (tid >= off) ? s[tid - off] : 0;
        int cur = s[tid];
        __syncthreads();
        s[tid] = cur + a;
        __syncthreads();
    }
    if (tid < SCAN_BLKS) bsums[tid] = s[tid] - v;
}

__global__ void k_scanC(int* __restrict__ out, const int* __restrict__ bsums) {
    int gid = blockIdx.x * 1024 + threadIdx.x;
    out[gid] += bsums[blockIdx.x];
}

// ---------------- pass 3: bucket -> padded CSR esrc ----------------
__global__ void k_p3_scatter(const int* __restrict__ bcursor, const int* __restrict__ ebuf,
                             const int* __restrict__ rowstart, int* __restrict__ esrc) {
    __shared__ int lcur[BWID];
    int b = blockIdx.x;
    int tid = threadIdx.x;
    int node0 = b * BWID;
    for (int i = tid; i < BWID; i += 256) lcur[i] = rowstart[node0 + i];
    __syncthreads();
    int size = bcursor[b];
    if (size > BCAP) size = BCAP;
    const int* eb = ebuf + b * BCAP;
    for (int k = tid; k < size; k += 256) {
        int v = eb[k];
        int local = v >> 18;
        int pos = atomicAdd(&lcur[local], 1);
        esrc[pos] = v & 0x3FFFF;
    }
    __syncthreads();
    for (int i = tid; i < BWID; i += 256) {
        int node = node0 + i;
        if (node < NN) {
            int end = rowstart[node + 1];
            for (int p = lcur[i]; p < end; p++) esrc[p] = NN;
        }
    }
}

// ---------------- dense matmul (layer 1 only): hws[n,32] = (X[n,K]@W)*invs ----------------
// LDS-staged X tile + 4-row x 4-channel register blocking.
// 128 threads, 64 rows/block (3125 exact blocks). Per k4 a wave issues 8
// ds_read_b128 feeding 128 VALU-cycles of FMA -> VALU-bound (was 6 reads /
// 64 cyc = LDS-issue-bound). Row ownership interleaved (g, g+16, g+32, g+48):
// group stride 132 words = 4 mod 32 -> x-read banks {4g} conflict-free.
template <int K>
__global__ void __launch_bounds__(128, 2) k_mm(const float* __restrict__ X,
                                               const float* __restrict__ W,
                                               const float* __restrict__ inv_sqrt,
                                               float* __restrict__ Y) {
    constexpr int K4 = K / 4;          // float4 per row
    constexpr int RS = K4 + 1;         // padded row stride in float4
    __shared__ float4 sW[K * 8];       // sW[k*8+q] = W[k][4q..4q+3]
    __shared__ float4 sX[64 * RS];
    int tid = threadIdx.x;
    for (int i = tid; i < K * 8; i += 128) sW[i] = ((const float4*)W)[i];
    const float4* __restrict__ Xg = (const float4*)(X + (size_t)blockIdx.x * 64 * K);
    for (int i = tid; i < 64 * K4; i += 128) {
        int row = i / K4;
        int col = i & (K4 - 1);
        sX[row * RS + col] = Xg[i];
    }
    __syncthreads();
    int g = tid >> 3;                  // 0..15, rows g, g+16, g+32, g+48
    int q = tid & 7;                   // channel quad (c = 4q..4q+3)
    const float4* __restrict__ xr0 = &sX[(size_t)(g + 0) * RS];
    const float4* __restrict__ xr1 = &sX[(size_t)(g + 16) * RS];
    const float4* __restrict__ xr2 = &sX[(size_t)(g + 32) * RS];
    const float4* __restrict__ xr3 = &sX[(size_t)(g + 48) * RS];
    float4 a0 = make_float4(0.f, 0.f, 0.f, 0.f);
    float4 a1 = make_float4(0.f, 0.f, 0.f, 0.f);
    float4 a2 = make_float4(0.f, 0.f, 0.f, 0.f);
    float4 a3 = make_float4(0.f, 0.f, 0.f, 0.f);
#pragma unroll 4
    for (int k4 = 0; k4 < K4; k4++) {
        float4 x0 = xr0[k4];
        float4 x1 = xr1[k4];
        float4 x2 = xr2[k4];
        float4 x3 = xr3[k4];
        const float4* wk = &sW[k4 * 32 + q];
#pragma unroll
        for (int kk = 0; kk < 4; kk++) {
            float4 w = wk[kk * 8];
            float s0 = (kk == 0) ? x0.x : (kk == 1) ? x0.y : (kk == 2) ? x0.z : x0.w;
            float s1 = (kk == 0) ? x1.x : (kk == 1) ? x1.y : (kk == 2) ? x1.z : x1.w;
            float s2 = (kk == 0) ? x2.x : (kk == 1) ? x2.y : (kk == 2) ? x2.z : x2.w;
            float s3 = (kk == 0) ? x3.x : (kk == 1) ? x3.y : (kk == 2) ? x3.z : x3.w;
            a0.x = fmaf(s0, w.x, a0.x); a0.y = fmaf(s0, w.y, a0.y);
            a0.z = fmaf(s0, w.z, a0.z); a0.w = fmaf(s0, w.w, a0.w);
            a1.x = fmaf(s1, w.x, a1.x); a1.y = fmaf(s1, w.y, a1.y);
            a1.z = fmaf(s1, w.z, a1.z); a1.w = fmaf(s1, w.w, a1.w);
            a2.x = fmaf(s2, w.x, a2.x); a2.y = fmaf(s2, w.y, a2.y);
            a2.z = fmaf(s2, w.z, a2.z); a2.w = fmaf(s2, w.w, a2.w);
            a3.x = fmaf(s3, w.x, a3.x); a3.y = fmaf(s3, w.y, a3.y);
            a3.z = fmaf(s3, w.z, a3.z); a3.w = fmaf(s3, w.w, a3.w);
        }
    }
    int n0 = blockIdx.x * 64 + g;
    float s0 = inv_sqrt[n0 + 0];
    float s1 = inv_sqrt[n0 + 16];
    float s2 = inv_sqrt[n0 + 32];
    float s3 = inv_sqrt[n0 + 48];
    a0.x *= s0; a0.y *= s0; a0.z *= s0; a0.w *= s0;
    a1.x *= s1; a1.y *= s1; a1.z *= s1; a1.w *= s1;
    a2.x *= s2; a2.y *= s2; a2.z *= s2; a2.w *= s2;
    a3.x *= s3; a3.y *= s3; a3.z *= s3; a3.w *= s3;
    ((float4*)(Y + (size_t)(n0 + 0) * 32))[q] = a0;
    ((float4*)(Y + (size_t)(n0 + 16) * 32))[q] = a1;
    ((float4*)(Y + (size_t)(n0 + 32) * 32))[q] = a2;
    ((float4*)(Y + (size_t)(n0 + 48) * 32))[q] = a3;
}

// ---------------- fused gather-aggregate + next-layer matmul ----------------
// Thread (n, c): gather-sum hws rows (padded CSR, conditional-free), tanh -> xout.
// MODE 1: also compute hnext[n][c] = invs[n] * sum_c' x[n][c'] * Wn[c'][c]
// MODE 2: hnext[n] = invs[n] * dot(x[n,:], Wn[0:32])  (shfl_xor reduce).
template <int MODE>
__global__ void k_aggr_f(const int* __restrict__ rowstart, const int* __restrict__ esrc,
                         const float* __restrict__ hws, const float* __restrict__ inv_sqrt,
                         const float* __restrict__ bvec, const float* __restrict__ Wn,
                         float* __restrict__ xout, float* __restrict__ hnext) {
    __shared__ float sxr[8][32];
    int t = blockIdx.x * 256 + threadIdx.x;
    int n = t >> 5, c = t & 31;
    int e0 = rowstart[n], e1 = rowstart[n + 1];
    float a[8];
    a[0] = hws[(size_t)n * 32 + c];
#pragma unroll
    for (int k = 1; k < 8; k++) a[k] = 0.0f;
    for (int e = e0; e < e1; e += 8) {
        int4 sA = *(const int4*)(esrc + e);
        int4 sB = *(const int4*)(esrc + e + 4);
        float v0 = hws[(size_t)sA.x * 32 + c];
        float v1 = hws[(size_t)sA.y * 32 + c];
        float v2 = hws[(size_t)sA.z * 32 + c];
        float v3 = hws[(size_t)sA.w * 32 + c];
        float v4 = hws[(size_t)sB.x * 32 + c];
        float v5 = hws[(size_t)sB.y * 32 + c];
        float v6 = hws[(size_t)sB.z * 32 + c];
        float v7 = hws[(size_t)sB.w * 32 + c];
        a[0] += v0; a[1] += v1; a[2] += v2; a[3] += v3;
        a[4] += v4; a[5] += v5; a[6] += v6; a[7] += v7;
    }
    float acc = ((a[0] + a[1]) + (a[2] + a[3])) + ((a[4] + a[5]) + (a[6] + a[7]));
    float invs = inv_sqrt[n];
    float r = tanhf(fmaf(acc, invs, bvec[c]));
    xout[t] = r;
    if (MODE == 1) {
        int ln = threadIdx.x >> 5;
        sxr[ln][c] = r;
        float wcol[32];
#pragma unroll
        for (int k = 0; k < 32; k++) wcol[k] = Wn[k * 32 + c];
        __syncthreads();
        const float4* xr = (const float4*)sxr[ln];
        float h = 0.f;
#pragma unroll
        for (int j = 0; j < 8; j++) {
            float4 xq = xr[j];
            h = fmaf(xq.x, wcol[4 * j + 0], h);
            h = fmaf(xq.y, wcol[4 * j + 1], h);
            h = fmaf(xq.z, wcol[4 * j + 2], h);
            h = fmaf(xq.w, wcol[4 * j + 3], h);
        }
        hnext[t] = h * invs;
    } else {
        float v = r * Wn[c];
        v += __shfl_xor(v, 1);
        v += __shfl_xor(v, 2);
        v += __shfl_xor(v, 4);
        v += __shfl_xor(v, 8);
        v += __shfl_xor(v, 16);
        if (c == 0) hnext[n] = v * invs;
        if (t == 0) hnext[NN] = 0.f;   // pad target for k_aggr1
    }
}

// layer-4 aggregation (1 channel), padded CSR: conditional-free
__global__ void k_aggr1(const int* __restrict__ rowstart, const int* __restrict__ esrc,
                        const float* __restrict__ hws4, const float* __restrict__ inv_sqrt,
                        const float* __restrict__ b4, float* __restrict__ x4) {
    int n = blockIdx.x * 256 + threadIdx.x;
    if (n >= NN) return;
    int e0 = rowstart[n], e1 = rowstart[n + 1];
    float a[8];
    a[0] = hws4[n];
#pragma unroll
    for (int k = 1; k < 8; k++) a[k] = 0.0f;
    for (int e = e0; e < e1; e += 8) {
        int4 sA = *(const int4*)(esrc + e);
        int4 sB = *(const int4*)(esrc + e + 4);
        a[0] += hws4[sA.x]; a[1] += hws4[sA.y];
        a[2] += hws4[sA.z]; a[3] += hws4[sA.w];
        a[4] += hws4[sB.x]; a[5] += hws4[sB.y];
        a[6] += hws4[sB.z]; a[7] += hws4[sB.w];
    }
    float acc = ((a[0] + a[1]) + (a[2] + a[3])) + ((a[4] + a[5]) + (a[6] + a[7]));
    x4[n] = tanhf(fmaf(acc, inv_sqrt[n], b4[0]));
}

// ---------------- graph boundaries from sorted batch (no atomics) ----------------
__global__ void k_gbounds(const int* __restrict__ batch, int* __restrict__ starts) {
    int n = blockIdx.x * 256 + threadIdx.x;
    if (n >= NN) return;
    int bn = batch[n];
    int bp = (n == 0) ? -1 : batch[n - 1];
    for (int g = bp + 1; g <= bn; g++) starts[g] = n;
    if (n == NN - 1)
        for (int g = bn + 1; g <= NG; g++) starts[g] = NN;
}

// ---------------- merged sort-pool + CNN/MLP head, one block per graph ----------------
__global__ void k_tail(const int* __restrict__ starts,
                       const float* __restrict__ x1, const float* __restrict__ x2,
                       const float* __restrict__ x3, const float* __restrict__ x4,
                       const float* __restrict__ w5, const float* __restrict__ b5,
                       const float* __restrict__ w6, const float* __restrict__ b6,
                       const float* __restrict__ fw1, const float* __restrict__ fb1,
                       const float* __restrict__ fw2, const float* __restrict__ fb2,
                       float* __restrict__ out) {
    __shared__ float keys[1024];
    __shared__ int sel[KSEL];
    __shared__ float sP[KSEL * CCAT];
    __shared__ float s5[16 * 30];
    __shared__ float smp[16 * 15];
    __shared__ float sz[352];
    __shared__ float sh[128];
    __shared__ float sl[10];
    int g = blockIdx.x;
    int tid = threadIdx.x;
    int start = starts[g];
    int cnt = starts[g + 1] - start;
    if (cnt > 1024) cnt = 1024;
    for (int i = tid; i < cnt; i += 256) keys[i] = x4[start + i];
    __syncthreads();
    for (int i = tid; i < cnt; i += 256) {
        float ki = keys[i];
        int rank = 0;
        for (int j = 0; j < cnt; j++) {
            float kj = keys[j];
            rank += (kj > ki) || (kj == ki && j < i);  // stable desc, matches lexsort
        }
        if (rank < KSEL) sel[rank] = start + i;
    }
    __syncthreads();
    int selcnt = cnt < KSEL ? cnt : KSEL;
    for (int t = tid; t < KSEL * CCAT; t += 256) {
        int r = t / CCAT, ch = t - r * CCAT;
        float v = 0.0f;
        if (r < selcnt) {
            int node = sel[r];
            if (ch < 32)      v = x1[(size_t)node * 32 + ch];
            else if (ch < 64) v = x2[(size_t)node * 32 + ch - 32];
            else if (ch < 96) v = x3[(size_t)node * 32 + ch - 64];
            else              v = x4[node];
        }
        sP[t] = v;
    }
    __syncthreads();
    for (int t = tid; t < 16 * 30; t += 256) {
        int c = t / 30, j = t - c * 30;
        float acc = b5[c];
        for (int i = 0; i < CCAT; i++) acc = fmaf(sP[j * CCAT + i], w5[c * CCAT + i], acc);
        s5[c * 30 + j] = fmaxf(acc, 0.0f);
    }
    __syncthreads();
    for (int t = tid; t < 16 * 15; t += 256) {
        int c = t / 15, j = t - c * 15;
        smp[t] = fmaxf(s5[c * 30 + 2 * j], s5[c * 30 + 2 * j + 1]);
    }
    __syncthreads();
    for (int t = tid; t < 32 * 11; t += 256) {
        int c = t / 11, j = t - c * 11;
        float acc = b6[c];
        for (int ci = 0; ci < 16; ci++) {
#pragma unroll
            for (int k = 0; k < 5; k++)
                acc = fmaf(smp[ci * 15 + j + k], w6[(c * 16 + ci) * 5 + k], acc);
        }
        sz[t] = fmaxf(acc, 0.0f);
    }
    __syncthreads();
    if (tid < 128) {
        float acc = fb1[tid];
        for (int i = 0; i < 352; i++) acc = fmaf(sz[i], fw1[i * 128 + tid], acc);
        sh[tid] = fmaxf(acc, 0.0f);
    }
    __syncthreads();
    if (tid < 10) {
        float acc = fb2[tid];
        for (int i = 0; i < 128; i++) acc = fmaf(sh[i], fw2[i * 10 + tid], acc);
        sl[tid] = acc;
    }
    __syncthreads();
    if (tid < 10) {
        float m = -1e30f;
        for (int i = 0; i < 10; i++) m = fmaxf(m, sl[i]);
        float ssum = 0.0f;
        for (int i = 0; i < 10; i++) ssum += expf(sl[i] - m);
        out[g * 10 + tid] = sl[tid] - m - logf(ssum);
    }
}

extern "C" void kernel_launch(void* const* d_in, const int* in_sizes, int n_in,
                              void* d_out, int out_size, void* d_ws, size_t ws_size,
                              hipStream_t stream) {
    const float* x   = (const float*)d_in[0];
    const int*   ei  = (const int*)d_in[1];
    const int*   bat = (const int*)d_in[2];
    const float* W1  = (const float*)d_in[3];
    const float* b1  = (const float*)d_in[4];
    const float* W2  = (const float*)d_in[5];
    const float* b2  = (const float*)d_in[6];
    const float* W3  = (const float*)d_in[7];
    const float* b3  = (const float*)d_in[8];
    const float* W4  = (const float*)d_in[9];
    const float* b4  = (const float*)d_in[10];
    const float* w5  = (const float*)d_in[11];
    const float* b5  = (const float*)d_in[12];
    const float* w6  = (const float*)d_in[13];
    const float* b6  = (const float*)d_in[14];
    const float* fw1 = (const float*)d_in[15];
    const float* fb1 = (const float*)d_in[16];
    const float* fw2 = (const float*)d_in[17];
    const float* fb2 = (const float*)d_in[18];
    float* out = (float*)d_out;

    float* ws = (float*)d_ws;
    float* inv_sqrt = ws;                             // NN
    float* hwsA     = inv_sqrt + NN;                  // (NN+1)*32, row NN = zero pad
    float* hwsB     = hwsA + (size_t)(NN + 1) * 32;   // (NN+1)*32, row NN = zero pad
    float* x1       = hwsB + (size_t)(NN + 1) * 32;   // NN*32
    float* x2       = x1 + (size_t)NN * 32;           // NN*32
    float* x3       = x2 + (size_t)NN * 32;           // NN*32
    float* x4       = x3 + (size_t)NN * 32;           // NN
    int* rowcnt     = (int*)(x4 + NN);                // NPAD
    int* rowstart   = rowcnt + NPAD;                  // NPAD
    int* esrc       = rowstart + NPAD;                // EPADCAP
    int* bcursor    = esrc + EPADCAP;                 // NB (pad to 512)
    int* bsums      = bcursor + 512;                  // 256
    int* gstarts    = bsums + 256;                    // NG+1 (pad to 1024)
    int* ebuf       = (int*)x3;                       // NB*BCAP ints (16 MB), dead before x3 written

    const int TB = 256;
    int gN  = (NN + TB - 1) / TB;
    int gNC = (NN * 32) / TB;      // exact: 25000
    int gMM = NN / 64;             // exact: 3125

    // ---- CSR build via bucketed partition ----
    hipMemsetAsync(bcursor, 0, 512 * sizeof(int), stream);
    hipMemsetAsync(rowcnt, 0, NPAD * sizeof(int), stream);
    hipMemsetAsync(hwsA + (size_t)NN * 32, 0, 32 * sizeof(float), stream);  // zero pad rows
    hipMemsetAsync(hwsB + (size_t)NN * 32, 0, 32 * sizeof(float), stream);
    k_p1_partition<<<P1_BLKS, TB, 0, stream>>>(ei, bcursor, ebuf);
    k_p2_count<<<NB, TB, 0, stream>>>(bcursor, ebuf, rowcnt, inv_sqrt);
    k_scanA<<<SCAN_BLKS, 1024, 0, stream>>>(rowcnt, rowstart, bsums);
    k_scanB<<<1, 256, 0, stream>>>(bsums);
    k_scanC<<<SCAN_BLKS, 1024, 0, stream>>>(rowstart, bsums);
    k_p3_scatter<<<NB, TB, 0, stream>>>(bcursor, ebuf, rowstart, esrc);

    // ---- graph boundaries (sorted batch -> no atomics) ----
    k_gbounds<<<gN, TB, 0, stream>>>(bat, gstarts);

    // ---- GCN layers (fused: aggr + next-layer matmul) ----
    k_mm<128><<<gMM, 128, 0, stream>>>(x, W1, inv_sqrt, hwsA);
    k_aggr_f<1><<<gNC, TB, 0, stream>>>(rowstart, esrc, hwsA, inv_sqrt, b1, W2, x1, hwsB);
    k_aggr_f<1><<<gNC, TB, 0, stream>>>(rowstart, esrc, hwsB, inv_sqrt, b2, W3, x2, hwsA);
    k_aggr_f<2><<<gNC, TB, 0, stream>>>(rowstart, esrc, hwsA, inv_sqrt, b3, W4, x3, hwsB);
    k_aggr1<<<gN, TB, 0, stream>>>(rowstart, esrc, hwsB, inv_sqrt, b4, x4);

    // ---- merged sort-pool + head ----
    k_tail<<<NG, TB, 0, stream>>>(gstarts, x1, x2, x3, x4,
                                  w5, b5, w6, b6, fw1, fb1, fw2, fb2, out);
}

// Round 10
// 570.151 us; speedup vs baseline: 1.0709x; 1.0709x over previous
//
#include <hip/hip_runtime.h>
#include <math.h>

#define NN 200000
#define NE 3200000
#define NF 128
#define NG 1000
#define KSEL 30
#define CCAT 97
#define EPADCAP (NE + 8 * NN)     // padded-CSR esrc capacity

#define BWID 512                  // nodes per bucket (dst >> 9)
#define NB 391                    // ceil(NN / BWID)
#define BCAP 10240                // per-bucket edge capacity (mean 8184, sigma ~90)
#define P1_CHUNK 8192             // edges per block in partition pass
#define P1_BLKS 391               // ceil(NE / P1_CHUNK)
#define GCUR 400                  // index of global cursor within bcursor array

// ---------------- pass 1: partition edges into dst-buckets ----------------
__global__ void k_p1_partition(const int* __restrict__ ei, int* __restrict__ bcursor,
                               int* __restrict__ ebuf) {
    __shared__ int lhist[NB];
    __shared__ int lbase[NB];
    int tid = threadIdx.x;
    int base = blockIdx.x * P1_CHUNK;
    for (int b = tid; b < NB; b += 256) lhist[b] = 0;
    __syncthreads();
    for (int it = 0; it < P1_CHUNK / 256; it++) {
        int e = base + it * 256 + tid;
        if (e < NE) {
            int s = ei[e], d = ei[NE + e];
            if (s != d) atomicAdd(&lhist[d >> 9], 1);
        }
    }
    __syncthreads();
    for (int b = tid; b < NB; b += 256) {
        int cnt = lhist[b];
        lbase[b] = cnt ? atomicAdd(&bcursor[b], cnt) : 0;
        lhist[b] = 0;
    }
    __syncthreads();
    for (int it = 0; it < P1_CHUNK / 256; it++) {
        int e = base + it * 256 + tid;
        if (e < NE) {
            int s = ei[e], d = ei[NE + e];
            if (s != d) {
                int b = d >> 9;
                int r = atomicAdd(&lhist[b], 1);
                int pos = lbase[b] + r;
                if (pos >= BCAP) pos = BCAP - 1;  // defensive (cannot happen)
                ebuf[b * BCAP + pos] = s | ((d & 511) << 18);
            }
        }
    }
}

// ---------------- pass 2: counts + DIRECT rowstart allocation ----------------
// Per-bucket region allocated with one atomicAdd on a global cursor; intra-
// bucket offsets via in-LDS 512-entry prefix scan (pair-per-thread). Rows are
// padded to x8. rowstart is NOT globally monotone (bucket order = completion
// order) -- rows only need private contiguous regions; end = start + rowcnt8.
// Also zeroes the hws pad rows (kills 2 memset dispatches) and inv_sqrt.
__global__ void k_p2_count(const int* __restrict__ bcursor, const int* __restrict__ ebuf,
                           int* __restrict__ rowstart, int* __restrict__ rowcnt8,
                           float* __restrict__ inv_sqrt, int* __restrict__ gcursor,
                           float* __restrict__ hwsA, float* __restrict__ hwsB) {
    __shared__ int lcnt[BWID];
    __shared__ int ps[256];
    __shared__ int sbase;
    int b = blockIdx.x;
    int tid = threadIdx.x;
    if (b == 0 && tid < 32) {          // zero pad rows of hwsA/hwsB
        hwsA[(size_t)NN * 32 + tid] = 0.0f;
        hwsB[(size_t)NN * 32 + tid] = 0.0f;
    }
    for (int i = tid; i < BWID; i += 256) lcnt[i] = 0;
    __syncthreads();
    int size = bcursor[b];
    if (size > BCAP) size = BCAP;
    const int* eb = ebuf + b * BCAP;
    for (int k = tid; k < size; k += 256) atomicAdd(&lcnt[eb[k] >> 18], 1);
    __syncthreads();
    int node0 = b * BWID;
    int i0 = 2 * tid, i1 = 2 * tid + 1;
    int c0raw = lcnt[i0], c1raw = lcnt[i1];
    int c0 = (node0 + i0 < NN) ? ((c0raw + 7) & ~7) : 0;
    int c1 = (node0 + i1 < NN) ? ((c1raw + 7) & ~7) : 0;
    int pair = c0 + c1;
    ps[tid] = pair;
    __syncthreads();
    for (int off = 1; off < 256; off <<= 1) {
        int a = (tid >= off) ? ps[tid - off] : 0;
        int cur = ps[tid];
        __syncthreads();
        ps[tid] = cur + a;
        __syncthreads();
    }
    if (tid == 255) sbase = atomicAdd(gcursor, ps[255]);
    int excl = ps[tid] - pair;
    __syncthreads();
    int rs0 = sbase + excl;
    int rs1 = rs0 + c0;
    int n0 = node0 + i0, n1 = node0 + i1;
    if (n0 < NN) {
        rowstart[n0] = rs0;
        rowcnt8[n0] = c0;
        inv_sqrt[n0] = rsqrtf((float)(c0raw + 1));
    }
    if (n1 < NN) {
        rowstart[n1] = rs1;
        rowcnt8[n1] = c1;
        inv_sqrt[n1] = rsqrtf((float)(c1raw + 1));
    }
}

// ---------------- pass 3: bucket -> padded CSR esrc ----------------
__global__ void k_p3_scatter(const int* __restrict__ bcursor, const int* __restrict__ ebuf,
                             const int* __restrict__ rowstart, const int* __restrict__ rowcnt8,
                             int* __restrict__ esrc) {
    __shared__ int lcur[BWID];
    int b = blockIdx.x;
    int tid = threadIdx.x;
    int node0 = b * BWID;
    for (int i = tid; i < BWID; i += 256)
        lcur[i] = (node0 + i < NN) ? rowstart[node0 + i] : 0;
    __syncthreads();
    int size = bcursor[b];
    if (size > BCAP) size = BCAP;
    const int* eb = ebuf + b * BCAP;
    for (int k = tid; k < size; k += 256) {
        int v = eb[k];
        int local = v >> 18;
        int pos = atomicAdd(&lcur[local], 1);
        esrc[pos] = v & 0x3FFFF;
    }
    __syncthreads();
    for (int i = tid; i < BWID; i += 256) {
        int node = node0 + i;
        if (node < NN) {
            int end = rowstart[node] + rowcnt8[node];
            for (int p = lcur[i]; p < end; p++) esrc[p] = NN;
        }
    }
}

// ---------------- dense matmul (layer 1 only): hws[n,32] = (X[n,K]@W)*invs ----------------
// Proven round-7 form: LDS-staged X tile, 256 threads, 64 rows/block,
// 2 rows x 4 channels per thread. LDS 50 KB -> 3 blocks/CU = 12 waves/CU.
template <int K>
__global__ void __launch_bounds__(256, 3) k_mm(const float* __restrict__ X,
                                               const float* __restrict__ W,
                                               const float* __restrict__ inv_sqrt,
                                               float* __restrict__ Y) {
    constexpr int K4 = K / 4;          // float4 per row
    constexpr int RS = K4 + 1;         // padded row stride in float4
    __shared__ float4 sW[K * 8];       // sW[k*8+q] = W[k][4q..4q+3]
    __shared__ float4 sX[64 * RS];
    int tid = threadIdx.x;
    for (int i = tid; i < K * 8; i += 256) sW[i] = ((const float4*)W)[i];
    const float4* __restrict__ Xg = (const float4*)(X + (size_t)blockIdx.x * 64 * K);
    for (int i = tid; i < 64 * K4; i += 256) {
        int row = i / K4;
        int col = i & (K4 - 1);
        sX[row * RS + col] = Xg[i];
    }
    __syncthreads();
    int g = tid >> 3;                  // 0..31, 2 rows each
    int q = tid & 7;                   // channel quad (c = 4q..4q+3)
    int r0 = blockIdx.x * 64 + g * 2;  // grid is exact: no bounds check needed
    const float4* __restrict__ xr0 = &sX[(size_t)(g * 2 + 0) * RS];
    const float4* __restrict__ xr1 = &sX[(size_t)(g * 2 + 1) * RS];
    float4 a0 = make_float4(0.f, 0.f, 0.f, 0.f);
    float4 a1 = make_float4(0.f, 0.f, 0.f, 0.f);
#pragma unroll 4
    for (int k4 = 0; k4 < K4; k4++) {
        float4 x0 = xr0[k4];
        float4 x1 = xr1[k4];
        const float4* wk = &sW[k4 * 32 + q];
#pragma unroll
        for (int kk = 0; kk < 4; kk++) {
            float4 w = wk[kk * 8];
            float s0 = (kk == 0) ? x0.x : (kk == 1) ? x0.y : (kk == 2) ? x0.z : x0.w;
            float s1 = (kk == 0) ? x1.x : (kk == 1) ? x1.y : (kk == 2) ? x1.z : x1.w;
            a0.x = fmaf(s0, w.x, a0.x); a0.y = fmaf(s0, w.y, a0.y);
            a0.z = fmaf(s0, w.z, a0.z); a0.w = fmaf(s0, w.w, a0.w);
            a1.x = fmaf(s1, w.x, a1.x); a1.y = fmaf(s1, w.y, a1.y);
            a1.z = fmaf(s1, w.z, a1.z); a1.w = fmaf(s1, w.w, a1.w);
        }
    }
    float s0 = inv_sqrt[r0 + 0];
    float s1 = inv_sqrt[r0 + 1];
    a0.x *= s0; a0.y *= s0; a0.z *= s0; a0.w *= s0;
    a1.x *= s1; a1.y *= s1; a1.z *= s1; a1.w *= s1;
    ((float4*)(Y + (size_t)(r0 + 0) * 32))[q] = a0;
    ((float4*)(Y + (size_t)(r0 + 1) * 32))[q] = a1;
}

// ---------------- fused gather-aggregate + next-layer matmul ----------------
// Thread (n, c): gather-sum hws rows (padded CSR, conditional-free), tanh -> xout.
// MODE 1: also hnext[n][c] = invs[n] * sum_c' x[n][c'] * Wn[c'][c]
// MODE 2: hnext[n] = invs[n] * dot(x[n,:], Wn[0:32])  (shfl_xor reduce).
template <int MODE>
__global__ void k_aggr_f(const int* __restrict__ rowstart, const int* __restrict__ rowcnt8,
                         const int* __restrict__ esrc,
                         const float* __restrict__ hws, const float* __restrict__ inv_sqrt,
                         const float* __restrict__ bvec, const float* __restrict__ Wn,
                         float* __restrict__ xout, float* __restrict__ hnext) {
    __shared__ float sxr[8][32];
    int t = blockIdx.x * 256 + threadIdx.x;
    int n = t >> 5, c = t & 31;
    int e0 = rowstart[n], e1 = e0 + rowcnt8[n];
    float a[8];
    a[0] = hws[(size_t)n * 32 + c];
#pragma unroll
    for (int k = 1; k < 8; k++) a[k] = 0.0f;
    for (int e = e0; e < e1; e += 8) {
        int4 sA = *(const int4*)(esrc + e);
        int4 sB = *(const int4*)(esrc + e + 4);
        float v0 = hws[(size_t)sA.x * 32 + c];
        float v1 = hws[(size_t)sA.y * 32 + c];
        float v2 = hws[(size_t)sA.z * 32 + c];
        float v3 = hws[(size_t)sA.w * 32 + c];
        float v4 = hws[(size_t)sB.x * 32 + c];
        float v5 = hws[(size_t)sB.y * 32 + c];
        float v6 = hws[(size_t)sB.z * 32 + c];
        float v7 = hws[(size_t)sB.w * 32 + c];
        a[0] += v0; a[1] += v1; a[2] += v2; a[3] += v3;
        a[4] += v4; a[5] += v5; a[6] += v6; a[7] += v7;
    }
    float acc = ((a[0] + a[1]) + (a[2] + a[3])) + ((a[4] + a[5]) + (a[6] + a[7]));
    float invs = inv_sqrt[n];
    float r = tanhf(fmaf(acc, invs, bvec[c]));
    xout[t] = r;
    if (MODE == 1) {
        int ln = threadIdx.x >> 5;
        sxr[ln][c] = r;
        float wcol[32];
#pragma unroll
        for (int k = 0; k < 32; k++) wcol[k] = Wn[k * 32 + c];
        __syncthreads();
        const float4* xr = (const float4*)sxr[ln];
        float h = 0.f;
#pragma unroll
        for (int j = 0; j < 8; j++) {
            float4 xq = xr[j];
            h = fmaf(xq.x, wcol[4 * j + 0], h);
            h = fmaf(xq.y, wcol[4 * j + 1], h);
            h = fmaf(xq.z, wcol[4 * j + 2], h);
            h = fmaf(xq.w, wcol[4 * j + 3], h);
        }
        hnext[t] = h * invs;
    } else {
        float v = r * Wn[c];
        v += __shfl_xor(v, 1);
        v += __shfl_xor(v, 2);
        v += __shfl_xor(v, 4);
        v += __shfl_xor(v, 8);
        v += __shfl_xor(v, 16);
        if (c == 0) hnext[n] = v * invs;
        if (t == 0) hnext[NN] = 0.f;   // pad target for k_aggr1
    }
}

// layer-4 aggregation (1 channel), padded CSR: conditional-free
__global__ void k_aggr1(const int* __restrict__ rowstart, const int* __restrict__ rowcnt8,
                        const int* __restrict__ esrc,
                        const float* __restrict__ hws4, const float* __restrict__ inv_sqrt,
                        const float* __restrict__ b4, float* __restrict__ x4) {
    int n = blockIdx.x * 256 + threadIdx.x;
    if (n >= NN) return;
    int e0 = rowstart[n], e1 = e0 + rowcnt8[n];
    float a[8];
    a[0] = hws4[n];
#pragma unroll
    for (int k = 1; k < 8; k++) a[k] = 0.0f;
    for (int e = e0; e < e1; e += 8) {
        int4 sA = *(const int4*)(esrc + e);
        int4 sB = *(const int4*)(esrc + e + 4);
        a[0] += hws4[sA.x]; a[1] += hws4[sA.y];
        a[2] += hws4[sA.z]; a[3] += hws4[sA.w];
        a[4] += hws4[sB.x]; a[5] += hws4[sB.y];
        a[6] += hws4[sB.z]; a[7] += hws4[sB.w];
    }
    float acc = ((a[0] + a[1]) + (a[2] + a[3])) + ((a[4] + a[5]) + (a[6] + a[7]));
    x4[n] = tanhf(fmaf(acc, inv_sqrt[n], b4[0]));
}

// ---------------- graph boundaries from sorted batch (no atomics) ----------------
__global__ void k_gbounds(const int* __restrict__ batch, int* __restrict__ starts) {
    int n = blockIdx.x * 256 + threadIdx.x;
    if (n >= NN) return;
    int bn = batch[n];
    int bp = (n == 0) ? -1 : batch[n - 1];
    for (int g = bp + 1; g <= bn; g++) starts[g] = n;
    if (n == NN - 1)
        for (int g = bn + 1; g <= NG; g++) starts[g] = NN;
}

// ---------------- merged sort-pool + CNN/MLP head, one block per graph ----------------
__global__ void k_tail(const int* __restrict__ starts,
                       const float* __restrict__ x1, const float* __restrict__ x2,
                       const float* __restrict__ x3, const float* __restrict__ x4,
                       const float* __restrict__ w5, const float* __restrict__ b5,
                       const float* __restrict__ w6, const float* __restrict__ b6,
                       const float* __restrict__ fw1, const float* __restrict__ fb1,
                       const float* __restrict__ fw2, const float* __restrict__ fb2,
                       float* __restrict__ out) {
    __shared__ float keys[1024];
    __shared__ int sel[KSEL];
    __shared__ float sP[KSEL * CCAT];
    __shared__ float s5[16 * 30];
    __shared__ float smp[16 * 15];
    __shared__ float sz[352];
    __shared__ float sh[128];
    __shared__ float sl[10];
    int g = blockIdx.x;
    int tid = threadIdx.x;
    int start = starts[g];
    int cnt = starts[g + 1] - start;
    if (cnt > 1024) cnt = 1024;
    for (int i = tid; i < cnt; i += 256) keys[i] = x4[start + i];
    __syncthreads();
    for (int i = tid; i < cnt; i += 256) {
        float ki = keys[i];
        int rank = 0;
        for (int j = 0; j < cnt; j++) {
            float kj = keys[j];
            rank += (kj > ki) || (kj == ki && j < i);  // stable desc, matches lexsort
        }
        if (rank < KSEL) sel[rank] = start + i;
    }
    __syncthreads();
    int selcnt = cnt < KSEL ? cnt : KSEL;
    for (int t = tid; t < KSEL * CCAT; t += 256) {
        int r = t / CCAT, ch = t - r * CCAT;
        float v = 0.0f;
        if (r < selcnt) {
            int node = sel[r];
            if (ch < 32)      v = x1[(size_t)node * 32 + ch];
            else if (ch < 64) v = x2[(size_t)node * 32 + ch - 32];
            else if (ch < 96) v = x3[(size_t)node * 32 + ch - 64];
            else              v = x4[node];
        }
        sP[t] = v;
    }
    __syncthreads();
    for (int t = tid; t < 16 * 30; t += 256) {
        int c = t / 30, j = t - c * 30;
        float acc = b5[c];
        for (int i = 0; i < CCAT; i++) acc = fmaf(sP[j * CCAT + i], w5[c * CCAT + i], acc);
        s5[c * 30 + j] = fmaxf(acc, 0.0f);
    }
    __syncthreads();
    for (int t = tid; t < 16 * 15; t += 256) {
        int c = t / 15, j = t - c * 15;
        smp[t] = fmaxf(s5[c * 30 + 2 * j], s5[c * 30 + 2 * j + 1]);
    }
    __syncthreads();
    for (int t = tid; t < 32 * 11; t += 256) {
        int c = t / 11, j = t - c * 11;
        float acc = b6[c];
        for (int ci = 0; ci < 16; ci++) {
#pragma unroll
            for (int k = 0; k < 5; k++)
                acc = fmaf(smp[ci * 15 + j + k], w6[(c * 16 + ci) * 5 + k], acc);
        }
        sz[t] = fmaxf(acc, 0.0f);
    }
    __syncthreads();
    if (tid < 128) {
        float acc = fb1[tid];
        for (int i = 0; i < 352; i++) acc = fmaf(sz[i], fw1[i * 128 + tid], acc);
        sh[tid] = fmaxf(acc, 0.0f);
    }
    __syncthreads();
    if (tid < 10) {
        float acc = fb2[tid];
        for (int i = 0; i < 128; i++) acc = fmaf(sh[i], fw2[i * 10 + tid], acc);
        sl[tid] = acc;
    }
    __syncthreads();
    if (tid < 10) {
        float m = -1e30f;
        for (int i = 0; i < 10; i++) m = fmaxf(m, sl[i]);
        float ssum = 0.0f;
        for (int i = 0; i < 10; i++) ssum += expf(sl[i] - m);
        out[g * 10 + tid] = sl[tid] - m - logf(ssum);
    }
}

extern "C" void kernel_launch(void* const* d_in, const int* in_sizes, int n_in,
                              void* d_out, int out_size, void* d_ws, size_t ws_size,
                              hipStream_t stream) {
    const float* x   = (const float*)d_in[0];
    const int*   ei  = (const int*)d_in[1];
    const int*   bat = (const int*)d_in[2];
    const float* W1  = (const float*)d_in[3];
    const float* b1  = (const float*)d_in[4];
    const float* W2  = (const float*)d_in[5];
    const float* b2  = (const float*)d_in[6];
    const float* W3  = (const float*)d_in[7];
    const float* b3  = (const float*)d_in[8];
    const float* W4  = (const float*)d_in[9];
    const float* b4  = (const float*)d_in[10];
    const float* w5  = (const float*)d_in[11];
    const float* b5  = (const float*)d_in[12];
    const float* w6  = (const float*)d_in[13];
    const float* b6  = (const float*)d_in[14];
    const float* fw1 = (const float*)d_in[15];
    const float* fb1 = (const float*)d_in[16];
    const float* fw2 = (const float*)d_in[17];
    const float* fb2 = (const float*)d_in[18];
    float* out = (float*)d_out;

    float* ws = (float*)d_ws;
    float* inv_sqrt = ws;                             // NN
    float* hwsA     = inv_sqrt + NN;                  // (NN+1)*32, row NN = zero pad
    float* hwsB     = hwsA + (size_t)(NN + 1) * 32;   // (NN+1)*32, row NN = zero pad
    float* x1       = hwsB + (size_t)(NN + 1) * 32;   // NN*32
    float* x2       = x1 + (size_t)NN * 32;           // NN*32
    float* x3       = x2 + (size_t)NN * 32;           // NN*32
    float* x4       = x3 + (size_t)NN * 32;           // NN
    int* rowstart   = (int*)(x4 + NN);                // NN (not monotone; private regions)
    int* rowcnt8    = rowstart + NN;                  // NN (padded row sizes)
    int* esrc       = rowcnt8 + NN;                   // EPADCAP
    int* bcursor    = esrc + EPADCAP;                 // NB + global cursor @ GCUR (512 total)
    int* gstarts    = bcursor + 512;                  // NG+1 (pad to 1024)
    int* ebuf       = (int*)x3;                       // NB*BCAP ints (16 MB), dead before x3 written

    const int TB = 256;
    int gN  = (NN + TB - 1) / TB;
    int gNC = (NN * 32) / TB;      // exact: 25000
    int gMM = NN / 64;             // exact: 3125

    // ---- CSR build via bucketed partition (scan-free: p2 allocates regions) ----
    hipMemsetAsync(bcursor, 0, 512 * sizeof(int), stream);
    k_p1_partition<<<P1_BLKS, TB, 0, stream>>>(ei, bcursor, ebuf);
    k_p2_count<<<NB, TB, 0, stream>>>(bcursor, ebuf, rowstart, rowcnt8, inv_sqrt,
                                      bcursor + GCUR, hwsA, hwsB);
    k_p3_scatter<<<NB, TB, 0, stream>>>(bcursor, ebuf, rowstart, rowcnt8, esrc);

    // ---- graph boundaries (sorted batch -> no atomics) ----
    k_gbounds<<<gN, TB, 0, stream>>>(bat, gstarts);

    // ---- GCN layers (fused: aggr + next-layer matmul) ----
    k_mm<128><<<gMM, TB, 0, stream>>>(x, W1, inv_sqrt, hwsA);
    k_aggr_f<1><<<gNC, TB, 0, stream>>>(rowstart, rowcnt8, esrc, hwsA, inv_sqrt, b1, W2, x1, hwsB);
    k_aggr_f<1><<<gNC, TB, 0, stream>>>(rowstart, rowcnt8, esrc, hwsB, inv_sqrt, b2, W3, x2, hwsA);
    k_aggr_f<2><<<gNC, TB, 0, stream>>>(rowstart, rowcnt8, esrc, hwsA, inv_sqrt, b3, W4, x3, hwsB);
    k_aggr1<<<gN, TB, 0, stream>>>(rowstart, rowcnt8, esrc, hwsB, inv_sqrt, b4, x4);

    // ---- merged sort-pool + head ----
    k_tail<<<NG, TB, 0, stream>>>(gstarts, x1, x2, x3, x4,
                                  w5, b5, w6, b6, fw1, fb1, fw2, fb2, out);
}

// Round 11
// 570.007 us; speedup vs baseline: 1.0712x; 1.0003x over previous
//
#include <hip/hip_runtime.h>
#include <math.h>

#define NN 200000
#define NE 3200000
#define NF 128
#define NG 1000
#define KSEL 30
#define CCAT 97
#define EPADCAP (NE + 8 * NN)     // padded-CSR esrc capacity

#define BWID 512                  // nodes per bucket (dst >> 9)
#define NB 391                    // ceil(NN / BWID)
#define BCAP 10240                // per-bucket edge capacity (mean 8184, sigma ~90)
#define P1_CHUNK 8192             // edges per block in partition pass
#define P1_BLKS 391               // ceil(NE / P1_CHUNK)
#define BPAD 3584                 // max padding per bucket (512 rows x 7)

// ---------------- pass 1: partition edges into dst-buckets ----------------
__global__ void k_p1_partition(const int* __restrict__ ei, int* __restrict__ bcursor,
                               int* __restrict__ ebuf) {
    __shared__ int lhist[NB];
    __shared__ int lbase[NB];
    int tid = threadIdx.x;
    int base = blockIdx.x * P1_CHUNK;
    for (int b = tid; b < NB; b += 256) lhist[b] = 0;
    __syncthreads();
    for (int it = 0; it < P1_CHUNK / 256; it++) {
        int e = base + it * 256 + tid;
        if (e < NE) {
            int s = ei[e], d = ei[NE + e];
            if (s != d) atomicAdd(&lhist[d >> 9], 1);
        }
    }
    __syncthreads();
    for (int b = tid; b < NB; b += 256) {
        int cnt = lhist[b];
        lbase[b] = cnt ? atomicAdd(&bcursor[b], cnt) : 0;
        lhist[b] = 0;
    }
    __syncthreads();
    for (int it = 0; it < P1_CHUNK / 256; it++) {
        int e = base + it * 256 + tid;
        if (e < NE) {
            int s = ei[e], d = ei[NE + e];
            if (s != d) {
                int b = d >> 9;
                int r = atomicAdd(&lhist[b], 1);
                int pos = lbase[b] + r;
                if (pos >= BCAP) pos = BCAP - 1;  // defensive (cannot happen)
                ebuf[b * BCAP + pos] = s | ((d & 511) << 18);
            }
        }
    }
}

// ---------------- bucket-base scan: bbase[b] = prefix(raw sizes) + b*BPAD ----------------
// One tiny block. Guarantees monotone, per-bucket-sufficient esrc regions:
// region b = [bbase[b], bbase[b+1]) has size raw_b + BPAD >= padded total.
__global__ void k_sb(const int* __restrict__ bcursor, int* __restrict__ bbase) {
    __shared__ int s[512];
    int tid = threadIdx.x;
    int v = (tid < NB) ? bcursor[tid] : 0;
    s[tid] = v;
    __syncthreads();
    for (int off = 1; off < 512; off <<= 1) {
        int a = (tid >= off) ? s[tid - off] : 0;
        int cur = s[tid];
        __syncthreads();
        s[tid] = cur + a;
        __syncthreads();
    }
    if (tid < NB) bbase[tid] = s[tid] - v + tid * BPAD;
}

// ---------------- pass 2: counts + monotone rowstart allocation ----------------
// Intra-bucket padded prefix via in-LDS pair-per-thread scan; base from bbase[b].
// rowstart is globally monotone (buckets are node-range-aligned).
// Also zeroes the hws pad rows (no memset dispatch).
__global__ void k_p2_count(const int* __restrict__ bcursor, const int* __restrict__ ebuf,
                           const int* __restrict__ bbase,
                           int* __restrict__ rowstart, int* __restrict__ rowcnt8,
                           float* __restrict__ inv_sqrt,
                           float* __restrict__ hwsA, float* __restrict__ hwsB) {
    __shared__ int lcnt[BWID];
    __shared__ int ps[256];
    int b = blockIdx.x;
    int tid = threadIdx.x;
    if (b == 0 && tid < 32) {          // zero pad rows of hwsA/hwsB
        hwsA[(size_t)NN * 32 + tid] = 0.0f;
        hwsB[(size_t)NN * 32 + tid] = 0.0f;
    }
    for (int i = tid; i < BWID; i += 256) lcnt[i] = 0;
    __syncthreads();
    int size = bcursor[b];
    if (size > BCAP) size = BCAP;
    const int* eb = ebuf + b * BCAP;
    for (int k = tid; k < size; k += 256) atomicAdd(&lcnt[eb[k] >> 18], 1);
    __syncthreads();
    int node0 = b * BWID;
    int i0 = 2 * tid, i1 = 2 * tid + 1;
    int c0raw = lcnt[i0], c1raw = lcnt[i1];
    int c0 = (node0 + i0 < NN) ? ((c0raw + 7) & ~7) : 0;
    int c1 = (node0 + i1 < NN) ? ((c1raw + 7) & ~7) : 0;
    int pair = c0 + c1;
    ps[tid] = pair;
    __syncthreads();
    for (int off = 1; off < 256; off <<= 1) {
        int a = (tid >= off) ? ps[tid - off] : 0;
        int cur = ps[tid];
        __syncthreads();
        ps[tid] = cur + a;
        __syncthreads();
    }
    int excl = ps[tid] - pair;
    int rs0 = bbase[b] + excl;
    int rs1 = rs0 + c0;
    int n0 = node0 + i0, n1 = node0 + i1;
    if (n0 < NN) {
        rowstart[n0] = rs0;
        rowcnt8[n0] = c0;
        inv_sqrt[n0] = rsqrtf((float)(c0raw + 1));
    }
    if (n1 < NN) {
        rowstart[n1] = rs1;
        rowcnt8[n1] = c1;
        inv_sqrt[n1] = rsqrtf((float)(c1raw + 1));
    }
}

// ---------------- pass 3: bucket -> padded CSR esrc ----------------
__global__ void k_p3_scatter(const int* __restrict__ bcursor, const int* __restrict__ ebuf,
                             const int* __restrict__ rowstart, const int* __restrict__ rowcnt8,
                             int* __restrict__ esrc) {
    __shared__ int lcur[BWID];
    int b = blockIdx.x;
    int tid = threadIdx.x;
    int node0 = b * BWID;
    for (int i = tid; i < BWID; i += 256)
        lcur[i] = (node0 + i < NN) ? rowstart[node0 + i] : 0;
    __syncthreads();
    int size = bcursor[b];
    if (size > BCAP) size = BCAP;
    const int* eb = ebuf + b * BCAP;
    for (int k = tid; k < size; k += 256) {
        int v = eb[k];
        int local = v >> 18;
        int pos = atomicAdd(&lcur[local], 1);
        esrc[pos] = v & 0x3FFFF;
    }
    __syncthreads();
    for (int i = tid; i < BWID; i += 256) {
        int node = node0 + i;
        if (node < NN) {
            int end = rowstart[node] + rowcnt8[node];
            for (int p = lcur[i]; p < end; p++) esrc[p] = NN;
        }
    }
}

// ---------------- dense matmul (layer 1 only): hws[n,32] = (X[n,K]@W)*invs ----------------
// Proven round-7 form: LDS-staged X tile, 256 threads, 64 rows/block,
// 2 rows x 4 channels per thread. LDS 50 KB -> 3 blocks/CU = 12 waves/CU.
template <int K>
__global__ void __launch_bounds__(256, 3) k_mm(const float* __restrict__ X,
                                               const float* __restrict__ W,
                                               const float* __restrict__ inv_sqrt,
                                               float* __restrict__ Y) {
    constexpr int K4 = K / 4;          // float4 per row
    constexpr int RS = K4 + 1;         // padded row stride in float4
    __shared__ float4 sW[K * 8];       // sW[k*8+q] = W[k][4q..4q+3]
    __shared__ float4 sX[64 * RS];
    int tid = threadIdx.x;
    for (int i = tid; i < K * 8; i += 256) sW[i] = ((const float4*)W)[i];
    const float4* __restrict__ Xg = (const float4*)(X + (size_t)blockIdx.x * 64 * K);
    for (int i = tid; i < 64 * K4; i += 256) {
        int row = i / K4;
        int col = i & (K4 - 1);
        sX[row * RS + col] = Xg[i];
    }
    __syncthreads();
    int g = tid >> 3;                  // 0..31, 2 rows each
    int q = tid & 7;                   // channel quad (c = 4q..4q+3)
    int r0 = blockIdx.x * 64 + g * 2;  // grid is exact: no bounds check needed
    const float4* __restrict__ xr0 = &sX[(size_t)(g * 2 + 0) * RS];
    const float4* __restrict__ xr1 = &sX[(size_t)(g * 2 + 1) * RS];
    float4 a0 = make_float4(0.f, 0.f, 0.f, 0.f);
    float4 a1 = make_float4(0.f, 0.f, 0.f, 0.f);
#pragma unroll 4
    for (int k4 = 0; k4 < K4; k4++) {
        float4 x0 = xr0[k4];
        float4 x1 = xr1[k4];
        const float4* wk = &sW[k4 * 32 + q];
#pragma unroll
        for (int kk = 0; kk < 4; kk++) {
            float4 w = wk[kk * 8];
            float s0 = (kk == 0) ? x0.x : (kk == 1) ? x0.y : (kk == 2) ? x0.z : x0.w;
            float s1 = (kk == 0) ? x1.x : (kk == 1) ? x1.y : (kk == 2) ? x1.z : x1.w;
            a0.x = fmaf(s0, w.x, a0.x); a0.y = fmaf(s0, w.y, a0.y);
            a0.z = fmaf(s0, w.z, a0.z); a0.w = fmaf(s0, w.w, a0.w);
            a1.x = fmaf(s1, w.x, a1.x); a1.y = fmaf(s1, w.y, a1.y);
            a1.z = fmaf(s1, w.z, a1.z); a1.w = fmaf(s1, w.w, a1.w);
        }
    }
    float s0 = inv_sqrt[r0 + 0];
    float s1 = inv_sqrt[r0 + 1];
    a0.x *= s0; a0.y *= s0; a0.z *= s0; a0.w *= s0;
    a1.x *= s1; a1.y *= s1; a1.z *= s1; a1.w *= s1;
    ((float4*)(Y + (size_t)(r0 + 0) * 32))[q] = a0;
    ((float4*)(Y + (size_t)(r0 + 1) * 32))[q] = a1;
}

// ---------------- fused gather-aggregate + next-layer matmul ----------------
// Thread (n, c): gather-sum hws rows (padded CSR, conditional-free), tanh -> xout.
// MODE 1: also hnext[n][c] = invs[n] * sum_c' x[n][c'] * Wn[c'][c]
// MODE 2: hnext[n] = invs[n] * dot(x[n,:], Wn[0:32])  (shfl_xor reduce).
template <int MODE>
__global__ void k_aggr_f(const int* __restrict__ rowstart, const int* __restrict__ rowcnt8,
                         const int* __restrict__ esrc,
                         const float* __restrict__ hws, const float* __restrict__ inv_sqrt,
                         const float* __restrict__ bvec, const float* __restrict__ Wn,
                         float* __restrict__ xout, float* __restrict__ hnext) {
    __shared__ float sxr[8][32];
    int t = blockIdx.x * 256 + threadIdx.x;
    int n = t >> 5, c = t & 31;
    int e0 = rowstart[n], e1 = e0 + rowcnt8[n];
    float a[8];
    a[0] = hws[(size_t)n * 32 + c];
#pragma unroll
    for (int k = 1; k < 8; k++) a[k] = 0.0f;
    for (int e = e0; e < e1; e += 8) {
        int4 sA = *(const int4*)(esrc + e);
        int4 sB = *(const int4*)(esrc + e + 4);
        float v0 = hws[(size_t)sA.x * 32 + c];
        float v1 = hws[(size_t)sA.y * 32 + c];
        float v2 = hws[(size_t)sA.z * 32 + c];
        float v3 = hws[(size_t)sA.w * 32 + c];
        float v4 = hws[(size_t)sB.x * 32 + c];
        float v5 = hws[(size_t)sB.y * 32 + c];
        float v6 = hws[(size_t)sB.z * 32 + c];
        float v7 = hws[(size_t)sB.w * 32 + c];
        a[0] += v0; a[1] += v1; a[2] += v2; a[3] += v3;
        a[4] += v4; a[5] += v5; a[6] += v6; a[7] += v7;
    }
    float acc = ((a[0] + a[1]) + (a[2] + a[3])) + ((a[4] + a[5]) + (a[6] + a[7]));
    float invs = inv_sqrt[n];
    float r = tanhf(fmaf(acc, invs, bvec[c]));
    xout[t] = r;
    if (MODE == 1) {
        int ln = threadIdx.x >> 5;
        sxr[ln][c] = r;
        float wcol[32];
#pragma unroll
        for (int k = 0; k < 32; k++) wcol[k] = Wn[k * 32 + c];
        __syncthreads();
        const float4* xr = (const float4*)sxr[ln];
        float h = 0.f;
#pragma unroll
        for (int j = 0; j < 8; j++) {
            float4 xq = xr[j];
            h = fmaf(xq.x, wcol[4 * j + 0], h);
            h = fmaf(xq.y, wcol[4 * j + 1], h);
            h = fmaf(xq.z, wcol[4 * j + 2], h);
            h = fmaf(xq.w, wcol[4 * j + 3], h);
        }
        hnext[t] = h * invs;
    } else {
        float v = r * Wn[c];
        v += __shfl_xor(v, 1);
        v += __shfl_xor(v, 2);
        v += __shfl_xor(v, 4);
        v += __shfl_xor(v, 8);
        v += __shfl_xor(v, 16);
        if (c == 0) hnext[n] = v * invs;
        if (t == 0) hnext[NN] = 0.f;   // pad target for k_aggr1
    }
}

// layer-4 aggregation (1 channel), padded CSR: conditional-free
__global__ void k_aggr1(const int* __restrict__ rowstart, const int* __restrict__ rowcnt8,
                        const int* __restrict__ esrc,
                        const float* __restrict__ hws4, const float* __restrict__ inv_sqrt,
                        const float* __restrict__ b4, float* __restrict__ x4) {
    int n = blockIdx.x * 256 + threadIdx.x;
    if (n >= NN) return;
    int e0 = rowstart[n], e1 = e0 + rowcnt8[n];
    float a[8];
    a[0] = hws4[n];
#pragma unroll
    for (int k = 1; k < 8; k++) a[k] = 0.0f;
    for (int e = e0; e < e1; e += 8) {
        int4 sA = *(const int4*)(esrc + e);
        int4 sB = *(const int4*)(esrc + e + 4);
        a[0] += hws4[sA.x]; a[1] += hws4[sA.y];
        a[2] += hws4[sA.z]; a[3] += hws4[sA.w];
        a[4] += hws4[sB.x]; a[5] += hws4[sB.y];
        a[6] += hws4[sB.z]; a[7] += hws4[sB.w];
    }
    float acc = ((a[0] + a[1]) + (a[2] + a[3])) + ((a[4] + a[5]) + (a[6] + a[7]));
    x4[n] = tanhf(fmaf(acc, inv_sqrt[n], b4[0]));
}

// ---------------- graph boundaries + bcursor zeroing (runs FIRST) ----------------
__global__ void k_gbounds(const int* __restrict__ batch, int* __restrict__ starts,
                          int* __restrict__ bcursor) {
    int tid = threadIdx.x;
    if (blockIdx.x == 0) {             // fold the bcursor memset in here
        bcursor[tid] = 0;
        bcursor[256 + tid] = 0;
    }
    int n = blockIdx.x * 256 + tid;
    if (n >= NN) return;
    int bn = batch[n];
    int bp = (n == 0) ? -1 : batch[n - 1];
    for (int g = bp + 1; g <= bn; g++) starts[g] = n;
    if (n == NN - 1)
        for (int g = bn + 1; g <= NG; g++) starts[g] = NN;
}

// ---------------- merged sort-pool + CNN/MLP head, one block per graph ----------------
__global__ void k_tail(const int* __restrict__ starts,
                       const float* __restrict__ x1, const float* __restrict__ x2,
                       const float* __restrict__ x3, const float* __restrict__ x4,
                       const float* __restrict__ w5, const float* __restrict__ b5,
                       const float* __restrict__ w6, const float* __restrict__ b6,
                       const float* __restrict__ fw1, const float* __restrict__ fb1,
                       const float* __restrict__ fw2, const float* __restrict__ fb2,
                       float* __restrict__ out) {
    __shared__ float keys[1024];
    __shared__ int sel[KSEL];
    __shared__ float sP[KSEL * CCAT];
    __shared__ float s5[16 * 30];
    __shared__ float smp[16 * 15];
    __shared__ float sz[352];
    __shared__ float sh[128];
    __shared__ float sl[10];
    int g = blockIdx.x;
    int tid = threadIdx.x;
    int start = starts[g];
    int cnt = starts[g + 1] - start;
    if (cnt > 1024) cnt = 1024;
    for (int i = tid; i < cnt; i += 256) keys[i] = x4[start + i];
    __syncthreads();
    for (int i = tid; i < cnt; i += 256) {
        float ki = keys[i];
        int rank = 0;
        for (int j = 0; j < cnt; j++) {
            float kj = keys[j];
            rank += (kj > ki) || (kj == ki && j < i);  // stable desc, matches lexsort
        }
        if (rank < KSEL) sel[rank] = start + i;
    }
    __syncthreads();
    int selcnt = cnt < KSEL ? cnt : KSEL;
    for (int t = tid; t < KSEL * CCAT; t += 256) {
        int r = t / CCAT, ch = t - r * CCAT;
        float v = 0.0f;
        if (r < selcnt) {
            int node = sel[r];
            if (ch < 32)      v = x1[(size_t)node * 32 + ch];
            else if (ch < 64) v = x2[(size_t)node * 32 + ch - 32];
            else if (ch < 96) v = x3[(size_t)node * 32 + ch - 64];
            else              v = x4[node];
        }
        sP[t] = v;
    }
    __syncthreads();
    for (int t = tid; t < 16 * 30; t += 256) {
        int c = t / 30, j = t - c * 30;
        float acc = b5[c];
        for (int i = 0; i < CCAT; i++) acc = fmaf(sP[j * CCAT + i], w5[c * CCAT + i], acc);
        s5[c * 30 + j] = fmaxf(acc, 0.0f);
    }
    __syncthreads();
    for (int t = tid; t < 16 * 15; t += 256) {
        int c = t / 15, j = t - c * 15;
        smp[t] = fmaxf(s5[c * 30 + 2 * j], s5[c * 30 + 2 * j + 1]);
    }
    __syncthreads();
    for (int t = tid; t < 32 * 11; t += 256) {
        int c = t / 11, j = t - c * 11;
        float acc = b6[c];
        for (int ci = 0; ci < 16; ci++) {
#pragma unroll
            for (int k = 0; k < 5; k++)
                acc = fmaf(smp[ci * 15 + j + k], w6[(c * 16 + ci) * 5 + k], acc);
        }
        sz[t] = fmaxf(acc, 0.0f);
    }
    __syncthreads();
    if (tid < 128) {
        float acc = fb1[tid];
        for (int i = 0; i < 352; i++) acc = fmaf(sz[i], fw1[i * 128 + tid], acc);
        sh[tid] = fmaxf(acc, 0.0f);
    }
    __syncthreads();
    if (tid < 10) {
        float acc = fb2[tid];
        for (int i = 0; i < 128; i++) acc = fmaf(sh[i], fw2[i * 10 + tid], acc);
        sl[tid] = acc;
    }
    __syncthreads();
    if (tid < 10) {
        float m = -1e30f;
        for (int i = 0; i < 10; i++) m = fmaxf(m, sl[i]);
        float ssum = 0.0f;
        for (int i = 0; i < 10; i++) ssum += expf(sl[i] - m);
        out[g * 10 + tid] = sl[tid] - m - logf(ssum);
    }
}

extern "C" void kernel_launch(void* const* d_in, const int* in_sizes, int n_in,
                              void* d_out, int out_size, void* d_ws, size_t ws_size,
                              hipStream_t stream) {
    const float* x   = (const float*)d_in[0];
    const int*   ei  = (const int*)d_in[1];
    const int*   bat = (const int*)d_in[2];
    const float* W1  = (const float*)d_in[3];
    const float* b1  = (const float*)d_in[4];
    const float* W2  = (const float*)d_in[5];
    const float* b2  = (const float*)d_in[6];
    const float* W3  = (const float*)d_in[7];
    const float* b3  = (const float*)d_in[8];
    const float* W4  = (const float*)d_in[9];
    const float* b4  = (const float*)d_in[10];
    const float* w5  = (const float*)d_in[11];
    const float* b5  = (const float*)d_in[12];
    const float* w6  = (const float*)d_in[13];
    const float* b6  = (const float*)d_in[14];
    const float* fw1 = (const float*)d_in[15];
    const float* fb1 = (const float*)d_in[16];
    const float* fw2 = (const float*)d_in[17];
    const float* fb2 = (const float*)d_in[18];
    float* out = (float*)d_out;

    float* ws = (float*)d_ws;
    float* inv_sqrt = ws;                             // NN
    float* hwsA     = inv_sqrt + NN;                  // (NN+1)*32, row NN = zero pad
    float* hwsB     = hwsA + (size_t)(NN + 1) * 32;   // (NN+1)*32, row NN = zero pad
    float* x1       = hwsB + (size_t)(NN + 1) * 32;   // NN*32
    float* x2       = x1 + (size_t)NN * 32;           // NN*32
    float* x3       = x2 + (size_t)NN * 32;           // NN*32
    float* x4       = x3 + (size_t)NN * 32;           // NN
    int* rowstart   = (int*)(x4 + NN);                // NN (monotone)
    int* rowcnt8    = rowstart + NN;                  // NN (padded row sizes)
    int* esrc       = rowcnt8 + NN;                   // EPADCAP
    int* bcursor    = esrc + EPADCAP;                 // 512 (NB raw sizes)
    int* bbase      = bcursor + 512;                  // 512 (bucket region bases)
    int* gstarts    = bbase + 512;                    // NG+1 (pad to 1024)
    int* ebuf       = (int*)x3;                       // NB*BCAP ints (16 MB), dead before x3 written

    const int TB = 256;
    int gN  = (NN + TB - 1) / TB;
    int gNC = (NN * 32) / TB;      // exact: 25000
    int gMM = NN / 64;             // exact: 3125

    // ---- graph boundaries + bcursor zeroing (independent, runs first) ----
    k_gbounds<<<gN, TB, 0, stream>>>(bat, gstarts, bcursor);

    // ---- CSR build via bucketed partition (scan-free, monotone regions) ----
    k_p1_partition<<<P1_BLKS, TB, 0, stream>>>(ei, bcursor, ebuf);
    k_sb<<<1, 512, 0, stream>>>(bcursor, bbase);
    k_p2_count<<<NB, TB, 0, stream>>>(bcursor, ebuf, bbase, rowstart, rowcnt8,
                                      inv_sqrt, hwsA, hwsB);
    k_p3_scatter<<<NB, TB, 0, stream>>>(bcursor, ebuf, rowstart, rowcnt8, esrc);

    // ---- GCN layers (fused: aggr + next-layer matmul) ----
    k_mm<128><<<gMM, TB, 0, stream>>>(x, W1, inv_sqrt, hwsA);
    k_aggr_f<1><<<gNC, TB, 0, stream>>>(rowstart, rowcnt8, esrc, hwsA, inv_sqrt, b1, W2, x1, hwsB);
    k_aggr_f<1><<<gNC, TB, 0, stream>>>(rowstart, rowcnt8, esrc, hwsB, inv_sqrt, b2, W3, x2, hwsA);
    k_aggr_f<2><<<gNC, TB, 0, stream>>>(rowstart, rowcnt8, esrc, hwsA, inv_sqrt, b3, W4, x3, hwsB);
    k_aggr1<<<gN, TB, 0, stream>>>(rowstart, rowcnt8, esrc, hwsB, inv_sqrt, b4, x4);

    // ---- merged sort-pool + head ----
    k_tail<<<NG, TB, 0, stream>>>(gstarts, x1, x2, x3, x4,
                                  w5, b5, w6, b6, fw1, fb1, fw2, fb2, out);
}